// Round 4
// baseline (470.570 us; speedup 1.0000x reference)
//
#include <hip/hip_runtime.h>
#include <math.h>

#define B_ 4
#define N_ 1024
#define C_ 512
#define H_ 8
#define HD_ 64
#define SCALE_ 0.125f
#define LN_EPS_ 1e-5f

typedef short bf16x8 __attribute__((ext_vector_type(8)));
typedef float f32x4 __attribute__((ext_vector_type(4)));

// Split 16 fp32 (2 k-half float4 groups) into hi/lo bf16 and store packed to LDS.
// hi = truncate-to-bf16 (RTZ), lo = exact residual truncated to bf16.
__device__ __forceinline__ void split_store16(unsigned short* __restrict__ Hh,
                                              unsigned short* __restrict__ Hl,
                                              int srow, int khalf,
                                              const float* __restrict__ f) {
    uint hp[8], lp[8];
#pragma unroll
    for (int i = 0; i < 8; ++i) {
        uint u0 = __float_as_uint(f[2 * i]);
        uint u1 = __float_as_uint(f[2 * i + 1]);
        uint h0 = u0 & 0xffff0000u;
        uint h1 = u1 & 0xffff0000u;
        float lo0 = f[2 * i]     - __uint_as_float(h0);
        float lo1 = f[2 * i + 1] - __uint_as_float(h1);
        hp[i] = (u0 >> 16) | (u1 & 0xffff0000u);
        lp[i] = (__float_as_uint(lo0) >> 16) | (__float_as_uint(lo1) & 0xffff0000u);
    }
    uint4* dh = (uint4*)&Hh[srow * 32 + khalf * 16];
    dh[0] = make_uint4(hp[0], hp[1], hp[2], hp[3]);
    dh[1] = make_uint4(hp[4], hp[5], hp[6], hp[7]);
    uint4* dl = (uint4*)&Hl[srow * 32 + khalf * 16];
    dl[0] = make_uint4(lp[0], lp[1], lp[2], lp[3]);
    dl[1] = make_uint4(lp[4], lp[5], lp[6], lp[7]);
}

// ---------------------------------------------------------------------------
// Kernel 1: qkv = x @ Wqkv + bqkv — split-bf16 MFMA, 128x128 tile, BK=32.
//   fp32 accuracy via 3-MFMA hi/lo decomposition per 16x16 tile k-step.
// ---------------------------------------------------------------------------
__global__ __launch_bounds__(256) void qkv_gemm_mfma(const float* __restrict__ x,
                                                     const float* __restrict__ Wqkv,
                                                     const float* __restrict__ bqkv,
                                                     float* __restrict__ qkv) {
    __shared__ __align__(16) unsigned short Ah[128 * 32];
    __shared__ __align__(16) unsigned short Al[128 * 32];
    __shared__ __align__(16) unsigned short Bh[128 * 32];
    __shared__ __align__(16) unsigned short Bl[128 * 32];

    const int tid = threadIdx.x;
    const int lane = tid & 63;
    const int wv = tid >> 6;
    const int wm = wv & 1, wn = wv >> 1;
    const int quad = lane >> 4, l15 = lane & 15;
    const int row0 = blockIdx.y * 128;
    const int col0 = blockIdx.x * 128;
    const int sr = tid >> 1;   // staging row 0..127
    const int kh = tid & 1;    // k-half

    f32x4 acc[4][4];
#pragma unroll
    for (int mt = 0; mt < 4; ++mt)
#pragma unroll
        for (int nt = 0; nt < 4; ++nt)
            acc[mt][nt] = (f32x4){0.f, 0.f, 0.f, 0.f};

    for (int kt = 0; kt < 512; kt += 32) {
        // global loads (before barrier, to overlap with previous compute)
        float a[16];
        {
            const float* ap = x + (size_t)(row0 + sr) * 512 + kt + kh * 16;
#pragma unroll
            for (int j = 0; j < 4; ++j) {
                float4 v = ((const float4*)ap)[j];
                a[j * 4 + 0] = v.x; a[j * 4 + 1] = v.y;
                a[j * 4 + 2] = v.z; a[j * 4 + 3] = v.w;
            }
        }
        float w[16];
        {
            const float* bp = Wqkv + (size_t)(kt + kh * 16) * 1536 + col0 + sr;
#pragma unroll
            for (int kk = 0; kk < 16; ++kk) w[kk] = bp[(size_t)kk * 1536];
        }
        __syncthreads();
        split_store16(Ah, Al, sr, kh, a);
        split_store16(Bh, Bl, sr, kh, w);
        __syncthreads();

        bf16x8 ah[4], al4[4], bh4[4], bl4[4];
#pragma unroll
        for (int mt = 0; mt < 4; ++mt) {
            int base = (wm * 64 + mt * 16 + l15) * 32 + quad * 8;
            ah[mt]  = *(const bf16x8*)&Ah[base];
            al4[mt] = *(const bf16x8*)&Al[base];
        }
#pragma unroll
        for (int nt = 0; nt < 4; ++nt) {
            int base = (wn * 64 + nt * 16 + l15) * 32 + quad * 8;
            bh4[nt] = *(const bf16x8*)&Bh[base];
            bl4[nt] = *(const bf16x8*)&Bl[base];
        }
#pragma unroll
        for (int mt = 0; mt < 4; ++mt)
#pragma unroll
            for (int nt = 0; nt < 4; ++nt) {
                acc[mt][nt] = __builtin_amdgcn_mfma_f32_16x16x32_bf16(
                    ah[mt], bh4[nt], acc[mt][nt], 0, 0, 0);
                acc[mt][nt] = __builtin_amdgcn_mfma_f32_16x16x32_bf16(
                    ah[mt], bl4[nt], acc[mt][nt], 0, 0, 0);
                acc[mt][nt] = __builtin_amdgcn_mfma_f32_16x16x32_bf16(
                    al4[mt], bh4[nt], acc[mt][nt], 0, 0, 0);
            }
    }

    // epilogue: +bias, store (C/D layout: col=lane&15, row=quad*4+reg)
#pragma unroll
    for (int nt = 0; nt < 4; ++nt) {
        int cg = col0 + wn * 64 + nt * 16 + l15;
        float bias = bqkv[cg];
#pragma unroll
        for (int mt = 0; mt < 4; ++mt) {
#pragma unroll
            for (int r = 0; r < 4; ++r) {
                int rg = row0 + wm * 64 + mt * 16 + quad * 4 + r;
                qkv[(size_t)rg * 1536 + cg] = acc[mt][nt][r] + bias;
            }
        }
    }
}

// ---------------------------------------------------------------------------
// Kernel 2: attn_scores — register-direct K (no K LDS staging, no main-loop
//   barriers). Block = (b,h, 16 query rows), 256 threads. Thread owns cols
//   {u*256+tid}; all 16 rows via broadcast float4 reads of Qst.
// ---------------------------------------------------------------------------
__global__ __launch_bounds__(256) void attn_scores(const float* __restrict__ qkv,
                                                   const float* __restrict__ ow_in,
                                                   float* __restrict__ attn) {
    __shared__ __align__(16) float Qst[64][20];  // [k][row], padded (16B-aligned rows)
    __shared__ float wred[16][5];                // [row][wave]

    const int tid = threadIdx.x;
    const int lane = tid & 63;
    const int wv = tid >> 6;
    const int n0 = blockIdx.x * 16;
    const int bh = blockIdx.y;
    const int b = bh >> 3, h = bh & 7;
    const size_t RS = 3 * C_;

    float w0 = ow_in[0], w1 = ow_in[1], w2 = ow_in[2];
    float wm = fmaxf(w0, fmaxf(w1, w2));
    float e0 = __expf(w0 - wm), e1 = __expf(w1 - wm), e2 = __expf(w2 - wm);
    float einv = 1.0f / (e0 + e1 + e2);
    float ow0 = e0 * einv, ow1 = e1 * einv, ow2 = e2 * einv;

    {   // stage Q tile k-major
        int r = tid >> 4, f = tid & 15;
        const float* qrow = qkv + (size_t)(b * N_ + n0 + r) * RS + h * HD_;
        float4 qv = ((const float4*)qrow)[f];
        Qst[f * 4 + 0][r] = qv.x; Qst[f * 4 + 1][r] = qv.y;
        Qst[f * 4 + 2][r] = qv.z; Qst[f * 4 + 3][r] = qv.w;
    }
    __syncthreads();

    float s[4][16];
#pragma unroll
    for (int u = 0; u < 4; ++u)
#pragma unroll
        for (int r = 0; r < 16; ++r) s[u][r] = 0.f;

    const float* kbase = qkv + (size_t)(b * N_) * RS + C_ + h * HD_;

    for (int k4 = 0; k4 < 16; ++k4) {
        float4 kv[4];
#pragma unroll
        for (int u = 0; u < 4; ++u)
            kv[u] = *(const float4*)(kbase + (size_t)(u * 256 + tid) * RS + k4 * 4);
#pragma unroll
        for (int kk = 0; kk < 4; ++kk) {
            float4 a0 = *(const float4*)&Qst[k4 * 4 + kk][0];
            float4 a1 = *(const float4*)&Qst[k4 * 4 + kk][4];
            float4 a2 = *(const float4*)&Qst[k4 * 4 + kk][8];
            float4 a3 = *(const float4*)&Qst[k4 * 4 + kk][12];
#pragma unroll
            for (int u = 0; u < 4; ++u) {
                const float* kvf = (const float*)&kv[u];
                float bv = kvf[kk];
                s[u][0]  += a0.x * bv; s[u][1]  += a0.y * bv;
                s[u][2]  += a0.z * bv; s[u][3]  += a0.w * bv;
                s[u][4]  += a1.x * bv; s[u][5]  += a1.y * bv;
                s[u][6]  += a1.z * bv; s[u][7]  += a1.w * bv;
                s[u][8]  += a2.x * bv; s[u][9]  += a2.y * bv;
                s[u][10] += a2.z * bv; s[u][11] += a2.w * bv;
                s[u][12] += a3.x * bv; s[u][13] += a3.y * bv;
                s[u][14] += a3.z * bv; s[u][15] += a3.w * bv;
            }
        }
    }

    // polynomial + per-row partial max
    float pm[16];
#pragma unroll
    for (int r = 0; r < 16; ++r) pm[r] = -1e30f;
#pragma unroll
    for (int u = 0; u < 4; ++u)
#pragma unroll
        for (int r = 0; r < 16; ++r) {
            float sc = s[u][r] * SCALE_;
            float l = sc * (ow0 + sc * (ow1 + sc * ow2));
            s[u][r] = l;
            pm[r] = fmaxf(pm[r], l);
        }

#pragma unroll
    for (int r = 0; r < 16; ++r)
#pragma unroll
        for (int m = 1; m < 64; m <<= 1)
            pm[r] = fmaxf(pm[r], __shfl_xor(pm[r], m, 64));
    if (lane == 0) {
#pragma unroll
        for (int r = 0; r < 16; ++r) wred[r][wv] = pm[r];
    }
    __syncthreads();
    float rowmax[16];
#pragma unroll
    for (int r = 0; r < 16; ++r)
        rowmax[r] = fmaxf(fmaxf(wred[r][0], wred[r][1]),
                          fmaxf(wred[r][2], wred[r][3]));

    float ps[16];
#pragma unroll
    for (int r = 0; r < 16; ++r) ps[r] = 0.f;
#pragma unroll
    for (int u = 0; u < 4; ++u)
#pragma unroll
        for (int r = 0; r < 16; ++r) {
            float e = __expf(s[u][r] - rowmax[r]);
            s[u][r] = e;
            ps[r] += e;
        }
    __syncthreads();  // protect wred reuse
#pragma unroll
    for (int r = 0; r < 16; ++r)
#pragma unroll
        for (int m = 1; m < 64; m <<= 1)
            ps[r] += __shfl_xor(ps[r], m, 64);
    if (lane == 0) {
#pragma unroll
        for (int r = 0; r < 16; ++r) wred[r][wv] = ps[r];
    }
    __syncthreads();
    float inv[16];
#pragma unroll
    for (int r = 0; r < 16; ++r)
        inv[r] = 1.0f / (wred[r][0] + wred[r][1] + wred[r][2] + wred[r][3]);

#pragma unroll
    for (int r = 0; r < 16; ++r) {
        float* orow = attn + ((size_t)bh * N_ + n0 + r) * N_;
#pragma unroll
        for (int u = 0; u < 4; ++u)
            orow[u * 256 + tid] = s[u][r] * inv[r];
    }
}

// ---------------------------------------------------------------------------
// Kernel 3: pv_gemm (unchanged)
// ---------------------------------------------------------------------------
__global__ __launch_bounds__(256) void pv_gemm(const float* __restrict__ qkv,
                                               const float* __restrict__ attn,
                                               float* __restrict__ ctx) {
    __shared__ __align__(16) float Pst[64][68];
    __shared__ __align__(16) float Vs[64][68];

    const int tid = threadIdx.x;
    const int tx = tid & 15;
    const int ty = tid >> 4;
    const int n0 = blockIdx.x * 64;
    const int bh = blockIdx.y;
    const int b = bh >> 3, h = bh & 7;
    const size_t RS = 3 * C_;

    const int rr = tid >> 2;
    const int q = tid & 3;

    float acc[4][4] = {};

    for (int mt = 0; mt < 16; ++mt) {
        const int m0 = mt * 64;
        const float* prow = attn + ((size_t)bh * N_ + n0 + rr) * N_ + m0 + q * 16;
        const float* vrow = qkv + (size_t)(b * N_ + m0 + rr) * RS + 2 * C_ + h * HD_ + q * 16;
        float4 pv[4], vv[4];
#pragma unroll
        for (int m = 0; m < 4; ++m) pv[m] = ((const float4*)prow)[m];
#pragma unroll
        for (int m = 0; m < 4; ++m) vv[m] = ((const float4*)vrow)[m];
        __syncthreads();
#pragma unroll
        for (int m = 0; m < 4; ++m) {
            int c = q * 16 + m * 4;
            Pst[c + 0][rr] = pv[m].x; Pst[c + 1][rr] = pv[m].y;
            Pst[c + 2][rr] = pv[m].z; Pst[c + 3][rr] = pv[m].w;
            *(float4*)&Vs[rr][c] = vv[m];
        }
        __syncthreads();
#pragma unroll 16
        for (int mm = 0; mm < 64; ++mm) {
            float4 a4 = *(const float4*)&Pst[mm][ty * 4];
            float4 b4 = *(const float4*)&Vs[mm][tx * 4];
            float a[4] = {a4.x, a4.y, a4.z, a4.w};
            float bb[4] = {b4.x, b4.y, b4.z, b4.w};
#pragma unroll
            for (int i = 0; i < 4; ++i)
#pragma unroll
                for (int j = 0; j < 4; ++j) acc[i][j] += a[i] * bb[j];
        }
    }
#pragma unroll
    for (int i = 0; i < 4; ++i) {
        float4 o;
        o.x = acc[i][0]; o.y = acc[i][1]; o.z = acc[i][2]; o.w = acc[i][3];
        *(float4*)&ctx[(size_t)(b * N_ + n0 + ty * 4 + i) * C_ + h * HD_ + tx * 4] = o;
    }
}

// ---------------------------------------------------------------------------
// Kernel 4: proj_gemm (unchanged)
// ---------------------------------------------------------------------------
__global__ __launch_bounds__(256) void proj_gemm(const float* __restrict__ ctx,
                                                 const float* __restrict__ x,
                                                 const float* __restrict__ Wproj,
                                                 const float* __restrict__ bproj,
                                                 float* __restrict__ y) {
    const int K = C_;
    const int NN = C_;
    __shared__ float As[64][17];
    __shared__ float Bs[16][64];

    const int tid = threadIdx.x;
    const int tx = tid & 15;
    const int ty = tid >> 4;
    const int row0 = blockIdx.y * 64;
    const int col0 = blockIdx.x * 64;

    float acc[4][4] = {};

    for (int kt = 0; kt < K; kt += 16) {
        {
            int lin = tid * 4;
            int m = lin >> 4;
            int k = lin & 15;
            float4 a = *(const float4*)&ctx[(size_t)(row0 + m) * K + kt + k];
            As[m][k + 0] = a.x; As[m][k + 1] = a.y;
            As[m][k + 2] = a.z; As[m][k + 3] = a.w;
        }
        {
            int lin = tid * 4;
            int kk = lin >> 6;
            int n = lin & 63;
            *(float4*)&Bs[kk][n] =
                *(const float4*)&Wproj[(size_t)(kt + kk) * NN + col0 + n];
        }
        __syncthreads();
#pragma unroll
        for (int kk = 0; kk < 16; ++kk) {
            float a[4], bb[4];
#pragma unroll
            for (int i = 0; i < 4; ++i) a[i] = As[ty * 4 + i][kk];
#pragma unroll
            for (int j = 0; j < 4; ++j) bb[j] = Bs[kk][tx * 4 + j];
#pragma unroll
            for (int i = 0; i < 4; ++i)
#pragma unroll
                for (int j = 0; j < 4; ++j) acc[i][j] += a[i] * bb[j];
        }
        __syncthreads();
    }
#pragma unroll
    for (int i = 0; i < 4; ++i) {
        int r = row0 + ty * 4 + i;
        int c = col0 + tx * 4;
        float4 xr = *(const float4*)&x[(size_t)r * C_ + c];
        float4 o;
        o.x = acc[i][0] + bproj[c + 0] + xr.x;
        o.y = acc[i][1] + bproj[c + 1] + xr.y;
        o.z = acc[i][2] + bproj[c + 2] + xr.z;
        o.w = acc[i][3] + bproj[c + 3] + xr.w;
        *(float4*)&y[(size_t)r * C_ + c] = o;
    }
}

// ---------------------------------------------------------------------------
// Kernel 5: ln_kernel (unchanged)
// ---------------------------------------------------------------------------
__global__ __launch_bounds__(256) void ln_kernel(float* __restrict__ y,
                                                 const float* __restrict__ gamma,
                                                 const float* __restrict__ beta) {
    __shared__ float wsum[4], wsq[4];
    const int row = blockIdx.x;
    const int tid = threadIdx.x;
    const int lane = tid & 63;
    const int w = tid >> 6;

    float2 v = ((const float2*)(y + (size_t)row * C_))[tid];
    float s = v.x + v.y;
    float sq = v.x * v.x + v.y * v.y;
#pragma unroll
    for (int m = 1; m < 64; m <<= 1) {
        s += __shfl_xor(s, m, 64);
        sq += __shfl_xor(sq, m, 64);
    }
    if (lane == 0) { wsum[w] = s; wsq[w] = sq; }
    __syncthreads();
    float ts = wsum[0] + wsum[1] + wsum[2] + wsum[3];
    float tq = wsq[0] + wsq[1] + wsq[2] + wsq[3];
    float mu = ts * (1.0f / C_);
    float var = tq * (1.0f / C_) - mu * mu;
    float rstd = rsqrtf(var + LN_EPS_);

    float2 g = ((const float2*)gamma)[tid];
    float2 be = ((const float2*)beta)[tid];
    float2 o;
    o.x = (v.x - mu) * rstd * g.x + be.x;
    o.y = (v.y - mu) * rstd * g.y + be.y;
    ((float2*)(y + (size_t)row * C_))[tid] = o;
}

extern "C" void kernel_launch(void* const* d_in, const int* in_sizes, int n_in,
                              void* d_out, int out_size, void* d_ws, size_t ws_size,
                              hipStream_t stream) {
    const float* x     = (const float*)d_in[0];
    const float* Wqkv  = (const float*)d_in[1];
    const float* bqkv  = (const float*)d_in[2];
    const float* ow    = (const float*)d_in[3];
    const float* Wproj = (const float*)d_in[4];
    const float* bproj = (const float*)d_in[5];
    const float* gamma = (const float*)d_in[6];
    const float* beta  = (const float*)d_in[7];

    float* out  = (float*)d_out;
    float* y    = out;                                  // [B,N,C]
    float* attn = out + (size_t)B_ * N_ * C_;           // [B,H,N,N]
    float* qkv  = (float*)d_ws;                         // [B*N, 3C]  25 MB
    float* ctx  = qkv + (size_t)B_ * N_ * 3 * C_;       // [B*N, C]    8 MB

    dim3 g1(3 * C_ / 128, B_ * N_ / 128);               // (12, 32)
    qkv_gemm_mfma<<<g1, 256, 0, stream>>>(x, Wqkv, bqkv, qkv);

    dim3 g2(N_ / 16, B_ * H_);                          // (64, 32)
    attn_scores<<<g2, 256, 0, stream>>>(qkv, ow, attn);

    dim3 g3(N_ / 64, B_ * H_);                          // (16, 32)
    pv_gemm<<<g3, 256, 0, stream>>>(qkv, attn, ctx);

    dim3 g4(C_ / 64, B_ * N_ / 64);                     // (8, 64)
    proj_gemm<<<g4, 256, 0, stream>>>(ctx, x, Wproj, bproj, y);

    ln_kernel<<<B_ * N_, 256, 0, stream>>>(y, gamma, beta);
}